// Round 9
// baseline (483.943 us; speedup 1.0000x reference)
//
#include <hip/hip_runtime.h>
#include <hip/hip_bf16.h>

#define B_   4
#define LQ_  1024
#define LK_  1024
#define LKL_ 512
#define DX_  1024
#define H_   16
#define DK_  64
#define HDK_ 1024
#define NEG_ -1e9f
#define EPS_ 1e-5f

typedef __bf16 bf16_t;
typedef __bf16 bf16x8 __attribute__((ext_vector_type(8)));
typedef __bf16 bf16x4 __attribute__((ext_vector_type(4)));
typedef float  f32x4  __attribute__((ext_vector_type(4)));

__device__ inline f32x4 mfma16(bf16x8 a, bf16x8 b, f32x4 c) {
    return __builtin_amdgcn_mfma_f32_16x16x32_bf16(a, b, c, 0, 0, 0);
}

__device__ __forceinline__ void gload16(const void* g, void* l) {
    __builtin_amdgcn_global_load_lds(
        (const __attribute__((address_space(1))) void*)g,
        (__attribute__((address_space(3))) void*)l, 16, 0, 0);
}

__device__ inline float waveMax(float v) {
#pragma unroll
    for (int o = 32; o > 0; o >>= 1) v = fmaxf(v, __shfl_xor(v, o, 64));
    return v;
}
__device__ inline float waveSum(float v) {
#pragma unroll
    for (int o = 32; o > 0; o >>= 1) v += __shfl_xor(v, o, 64);
    return v;
}

// XOR-swizzle: spread column-slice reads across banks (16B slots XOR row).
template<int STRIDE>
__device__ inline int sidx(int row, int col) {
    return (row * STRIDE + col) ^ ((row & 15) << 3);
}

// ---------------------------------------------------------------------------
// Bit-pack both masks (1 = masked), with inline dtype detection.
// ---------------------------------------------------------------------------
__global__ __launch_bounds__(256) void bitpack_mask_kernel(
    const void* __restrict__ mc, const void* __restrict__ ml,
    unsigned long long* __restrict__ bc, unsigned long long* __restrict__ bl)
{
    __shared__ unsigned fl[4];
    {
        const unsigned w = ((const unsigned*)mc)[threadIdx.x];
        const unsigned long long b01 = __ballot(w <= 1u);
        const unsigned long long bfl = __ballot(w == 0u || w == 0x3F800000u);
        if ((threadIdx.x & 63) == 0)
            fl[threadIdx.x >> 6] = ((b01 == ~0ull) ? 1u : 0u) | ((bfl == ~0ull) ? 2u : 0u);
    }
    __syncthreads();
    const unsigned comb = fl[0] & fl[1] & fl[2] & fl[3];
    const unsigned flag = (comb & 1u) ? 0u : ((comb & 2u) ? 2u : 1u);

    const size_t NC = (size_t)B_ * LQ_ * LK_;
    const int lane = threadIdx.x & 63;
    const size_t g = (size_t)blockIdx.x * 256 + threadIdx.x;
    const bool inC = g < NC;
    const size_t idx = inC ? g : g - NC;
    const void* src = inC ? mc : ml;
    bool m;
    if (flag == 0u)      m = ((const int*)src)[idx] != 0;
    else if (flag == 2u) m = ((const float*)src)[idx] != 0.0f;
    else                 m = ((const unsigned char*)src)[idx] != 0;
    const unsigned long long bal = __ballot(m);
    if (lane == 0) {
        unsigned long long* dst = inC ? bc : bl;
        dst[idx >> 6] = bal;
    }
}

// ---------------------------------------------------------------------------
// All activation f32 -> bf16 conversions in one launch (y picks tensor).
// ---------------------------------------------------------------------------
struct CvtArgs {
    const float* src[5];
    bf16_t* dst[5];
    int n8[5];
};
__global__ __launch_bounds__(256) void cvt_all_kernel(CvtArgs a)
{
    const int z = blockIdx.y;
    const int i = blockIdx.x * 256 + threadIdx.x;
    if (i >= a.n8[z]) return;
    const float* src = a.src[z];
    const float4 x = ((const float4*)src)[i * 2];
    const float4 y = ((const float4*)src)[i * 2 + 1];
    bf16x8 o;
    o[0] = (bf16_t)x.x; o[1] = (bf16_t)x.y; o[2] = (bf16_t)x.z; o[3] = (bf16_t)x.w;
    o[4] = (bf16_t)y.x; o[5] = (bf16_t)y.y; o[6] = (bf16_t)y.z; o[7] = (bf16_t)y.w;
    ((bf16x8*)a.dst[z])[i] = o;
}

// ---------------------------------------------------------------------------
// All 6 weight transposes (KxN f32 -> NxK bf16) in one launch.
// ---------------------------------------------------------------------------
struct WtArgs {
    const float* W[6];
    bf16_t* Wt[6];
};
__global__ __launch_bounds__(256) void wtrans_all_kernel(WtArgs a)
{
    __shared__ float T[64][65];
    const int z = blockIdx.z;
    const float* W = a.W[z];
    bf16_t* Wt = a.Wt[z];
    const int k0 = blockIdx.y * 64, n0 = blockIdx.x * 64;
    const int t = threadIdx.x;
    const int lr = t >> 2, c0 = (t & 3) * 16;
#pragma unroll
    for (int j = 0; j < 4; ++j) {
        const float4 v = *(const float4*)&W[(size_t)(k0 + lr) * DX_ + n0 + c0 + j * 4];
        T[lr][c0 + j * 4 + 0] = v.x; T[lr][c0 + j * 4 + 1] = v.y;
        T[lr][c0 + j * 4 + 2] = v.z; T[lr][c0 + j * 4 + 3] = v.w;
    }
    __syncthreads();
    const int dr = t >> 2;
    bf16x8 o0, o1;
#pragma unroll
    for (int j = 0; j < 8; ++j) {
        o0[j] = (bf16_t)T[c0 + j][dr];
        o1[j] = (bf16_t)T[c0 + 8 + j][dr];
    }
    *(bf16x8*)&Wt[(size_t)(n0 + dr) * DX_ + k0 + c0]     = o0;
    *(bf16x8*)&Wt[(size_t)(n0 + dr) * DX_ + k0 + c0 + 8] = o1;
}

// ---------------------------------------------------------------------------
// Both V transposes (bh, L, 64) -> (bh, 64, L) in one launch.
// ---------------------------------------------------------------------------
struct TvArgs {
    const bf16_t* V[2];
    bf16_t* Vt[2];
    int L[2];
    int xt[2];
};
__global__ __launch_bounds__(256) void transpose_v_all_kernel(TvArgs a)
{
    __shared__ bf16_t T[64][72];
    const int z = blockIdx.z;
    if ((int)blockIdx.x >= a.xt[z]) return;
    const int L = a.L[z];
    const int bh = blockIdx.y, l0 = blockIdx.x * 64;
    const bf16_t* Vb = a.V[z] + (size_t)bh * L * 64;
    bf16_t* Vtb = a.Vt[z] + (size_t)bh * 64 * L;
    const int t = threadIdx.x;
    {
        const int lr = t >> 2, dc = (t & 3) * 16;
        const bf16x8 x = *(const bf16x8*)&Vb[(size_t)(l0 + lr) * 64 + dc];
        const bf16x8 y = *(const bf16x8*)&Vb[(size_t)(l0 + lr) * 64 + dc + 8];
#pragma unroll
        for (int j = 0; j < 8; ++j) { T[lr][dc + j] = x[j]; T[lr][dc + 8 + j] = y[j]; }
    }
    __syncthreads();
    {
        const int dr = t >> 2, lc = (t & 3) * 16;
        bf16x8 o0, o1;
#pragma unroll
        for (int j = 0; j < 8; ++j) { o0[j] = T[lc + j][dr]; o1[j] = T[lc + 8 + j][dr]; }
        *(bf16x8*)&Vtb[(size_t)dr * L + l0 + lc]     = o0;
        *(bf16x8*)&Vtb[(size_t)dr * L + l0 + lc + 8] = o1;
    }
}

// ---------------------------------------------------------------------------
// m97-style GEMM core (128x128 tile, BK=64, 512 threads, global_load_lds,
// XOR-swizzled LDS, conflict-free ds_read_b128).
// ---------------------------------------------------------------------------
template<int MODE>   // 0: bf16 head layout.  2: f32 + residual, A = Ac + Al
__device__ __forceinline__ void gemm2_body(
    const bf16_t* __restrict__ A, const bf16_t* __restrict__ A2,
    const bf16_t* __restrict__ Bt,
    const float* __restrict__ bias,
    void* __restrict__ out, const float* __restrict__ resid, int lshift,
    bf16_t* __restrict__ As, bf16_t* __restrict__ Bs)
{
    char* const AsB = (char*)As;
    char* const BsB = (char*)Bs;
    const int tid = threadIdx.x, wave = tid >> 6, lane = tid & 63;
    const int m0 = blockIdx.y * 128, n0 = blockIdx.x * 128;
    const int wr4 = (wave >> 1) * 32, wc2 = (wave & 1) * 64;

    f32x4 acc[2][4] = {};

    const int srow = wave * 8 + (lane >> 3);
    const int sslot = lane & 7;

    for (int k0 = 0; k0 < 1024; k0 += 64) {
        __syncthreads();
#pragma unroll
        for (int j = 0; j < 2; ++j) {
            const int row = srow + j * 64;
            const int gs = sslot ^ (row & 7);
            if (MODE == 0) {
                gload16(&A[(size_t)(m0 + row) * 1024 + k0 + gs * 8],
                        AsB + j * 8192 + wave * 1024);
            } else {
                const bf16x8 ac = *(const bf16x8*)&A [(size_t)(m0 + row) * 1024 + k0 + gs * 8];
                const bf16x8 al = *(const bf16x8*)&A2[(size_t)(m0 + row) * 1024 + k0 + gs * 8];
                bf16x8 sum;
#pragma unroll
                for (int jj = 0; jj < 8; ++jj)
                    sum[jj] = (bf16_t)((float)ac[jj] + (float)al[jj]);
                *(bf16x8*)(AsB + j * 8192 + wave * 1024 + (lane & 63) * 16) = sum;
            }
            gload16(&Bt[(size_t)(n0 + row) * 1024 + k0 + gs * 8],
                    BsB + j * 8192 + wave * 1024);
        }
        __syncthreads();
#pragma unroll
        for (int kk = 0; kk < 2; ++kk) {
            bf16x8 av[2], bv[4];
#pragma unroll
            for (int i = 0; i < 2; ++i) {
                const int r = wr4 + i * 16 + (lane & 15);
                av[i] = *(const bf16x8*)(AsB + r * 128 + (((kk * 4 + (lane >> 4)) ^ (r & 7)) * 16));
            }
#pragma unroll
            for (int n = 0; n < 4; ++n) {
                const int r = wc2 + n * 16 + (lane & 15);
                bv[n] = *(const bf16x8*)(BsB + r * 128 + (((kk * 4 + (lane >> 4)) ^ (r & 7)) * 16));
            }
#pragma unroll
            for (int i = 0; i < 2; ++i)
#pragma unroll
                for (int n = 0; n < 4; ++n)
                    acc[i][n] = mfma16(av[i], bv[n], acc[i][n]);
        }
    }

#pragma unroll
    for (int i = 0; i < 2; ++i) {
#pragma unroll
        for (int n = 0; n < 4; ++n) {
            const int col = n0 + wc2 + n * 16 + (lane & 15);
            const float bs = bias[col];
            const int row0 = m0 + wr4 + i * 16 + (lane >> 4) * 4;
            if (MODE == 0) {
                const int b = row0 >> lshift, l = row0 & ((1 << lshift) - 1);
                const int h = col >> 6, d = col & 63;
#pragma unroll
                for (int r = 0; r < 4; ++r)
                    ((bf16_t*)out)[(((size_t)(b * H_ + h) << lshift) + l + r) * DK_ + d] =
                        (bf16_t)(acc[i][n][r] + bs);
            } else {
#pragma unroll
                for (int r = 0; r < 4; ++r) {
                    const size_t idx = (size_t)(row0 + r) * DX_ + col;
                    ((float*)out)[idx] = acc[i][n][r] + bs + resid[idx];
                }
            }
        }
    }
}

// All 5 projection GEMMs in one launch (z picks operands).
struct ProjArgs {
    const bf16_t* A[5];
    const bf16_t* Bt[5];
    const float* bias[5];
    bf16_t* out[5];
    int mt[5];
    int lshift[5];
};
__global__ __launch_bounds__(512, 2) void proj_gemm_kernel(ProjArgs a)
{
    __shared__ bf16_t As[128 * 64];
    __shared__ bf16_t Bs[128 * 64];
    const int z = blockIdx.z;
    if ((int)blockIdx.y >= a.mt[z]) return;
    gemm2_body<0>(a.A[z], nullptr, a.Bt[z], a.bias[z], a.out[z], nullptr, a.lshift[z], As, Bs);
}

// Output projection + bias + residual; A = comb_c + comb_l (reg-staged).
__global__ __launch_bounds__(512, 2) void out_gemm_kernel(
    const bf16_t* __restrict__ Ac, const bf16_t* __restrict__ Al,
    const bf16_t* __restrict__ Bt,
    const float* __restrict__ bias, float* __restrict__ out,
    const float* __restrict__ resid)
{
    __shared__ bf16_t As[128 * 64];
    __shared__ bf16_t Bs[128 * 64];
    gemm2_body<2>(Ac, Al, Bt, bias, out, resid, 0, As, Bs);
}

// ---------------------------------------------------------------------------
// Attention branch body: 16 q-rows/block, 4 waves. Mask bits read directly
// from global (L2-hot, broadcast). Scores->LDS; barrier; register softmax
// (bf16 probs -> LDS); barrier; PV; comb store; prob stream-out last.
// ---------------------------------------------------------------------------
template<int LKX>
__device__ __forceinline__ void fused_branch_body(
    const bf16_t* __restrict__ Qh, const bf16_t* __restrict__ Kh,
    const bf16_t* __restrict__ Vt, const unsigned* __restrict__ bits,
    float* __restrict__ S, bf16_t* __restrict__ comb,
    bf16_t* __restrict__ Ssh, int sid)
{
    const int bh = sid >> 6, qt = sid & 63;
    const int b = bh >> 4, h = bh & 15;
    const int q0 = qt * 16;
    const int wave = threadIdx.x >> 6, lane = threadIdx.x & 63;
    const int lr = lane & 15, lk8 = (lane >> 4) * 8;
    constexpr int WORDS = LKX / 32;

    const bf16_t* Qb  = Qh + (size_t)bh * LQ_ * DK_;
    const bf16_t* Kb  = Kh + (size_t)bh * LKX * DK_;
    const bf16_t* Vtb = Vt + (size_t)bh * DK_ * LKX;
    float* Sout = S + (size_t)bh * LQ_ * LKX;

    bf16x8 qf[2];
#pragma unroll
    for (int ks = 0; ks < 2; ++ks)
        qf[ks] = *(const bf16x8*)&Qb[(size_t)(q0 + lr) * DK_ + ks * 32 + lk8];

    // ---- scores (masked at write-back; bits from global, 16-lane bcast) ----
    constexpr int KTS = LKX / 64;
#pragma unroll
    for (int kt = 0; kt < KTS; ++kt) {
        const int kbase = wave * (LKX / 4) + kt * 16;
        const bf16x8 b0 = *(const bf16x8*)&Kb[(size_t)(kbase + lr) * DK_ + lk8];
        const bf16x8 b1 = *(const bf16x8*)&Kb[(size_t)(kbase + lr) * DK_ + 32 + lk8];
        f32x4 acc = {};
        acc = mfma16(qf[0], b0, acc);
        acc = mfma16(qf[1], b1, acc);
        const int wi = kbase >> 5;
        const int sh = (kbase & 16) + (lane & 15);
#pragma unroll
        for (int r = 0; r < 4; ++r) {
            const int row = (lane >> 4) * 4 + r;
            const unsigned word = bits[(size_t)(b * LQ_ + q0 + row) * WORDS + wi];
            const bool msk = (word >> sh) & 1u;
            Ssh[sidx<LKX>(row, kbase + (lane & 15))] = (bf16_t)(msk ? NEG_ : acc[r] * 0.125f);
        }
    }
    __syncthreads();

    // ---- softmax: 4 rows/wave, unroll 2 for shuffle-chain ILP; LDS-only out
    constexpr int NP8 = LKX / 512;
#pragma unroll 2
    for (int i = 0; i < 4; ++i) {
        const int row = wave * 4 + i;
        float p[NP8 * 8];
        float m = -INFINITY;
#pragma unroll
        for (int ps = 0; ps < NP8; ++ps) {
            const bf16x8 sv = *(const bf16x8*)&Ssh[sidx<LKX>(row, ps * 512 + lane * 8)];
#pragma unroll
            for (int j = 0; j < 8; ++j) {
                p[ps * 8 + j] = (float)sv[j];
                m = fmaxf(m, p[ps * 8 + j]);
            }
        }
        m = waveMax(m);
        float s = 0.f;
#pragma unroll
        for (int j = 0; j < NP8 * 8; ++j) { p[j] = __expf(p[j] - m); s += p[j]; }
        s = waveSum(s);
        const float inv = 1.f / s;
#pragma unroll
        for (int ps = 0; ps < NP8; ++ps) {
            const int col = ps * 512 + lane * 8;
            bf16x8 pb;
#pragma unroll
            for (int j = 0; j < 8; ++j) pb[j] = (bf16_t)(p[ps * 8 + j] * inv);
            *(bf16x8*)&Ssh[sidx<LKX>(row, col)] = pb;
        }
    }
    __syncthreads();

    // ---- PV ----
    f32x4 acc_o = {};
    const int d0 = wave * 16;
#pragma unroll
    for (int ks = 0; ks < LKX / 32; ++ks) {
        const bf16x8 bb = *(const bf16x8*)&Vtb[(size_t)(d0 + lr) * LKX + ks * 32 + lk8];
        const bf16x8 a  = *(const bf16x8*)&Ssh[sidx<LKX>(lr, ks * 32 + lk8)];
        acc_o = mfma16(a, bb, acc_o);
    }

    // ---- epilogue: comb (own buffer, plain store) ----
#pragma unroll
    for (int r = 0; r < 4; ++r) {
        const int row = q0 + (lane >> 4) * 4 + r;
        const size_t idx = ((size_t)b * LQ_ + row) * HDK_ + h * DK_ + d0 + (lane & 15);
        comb[idx] = (bf16_t)(0.5f * acc_o[r]);
    }

    // ---- prob stream-out (after last barrier; fire-and-forget) ----
#pragma unroll
    for (int i = 0; i < 4; ++i) {
        const int row = wave * 4 + i;
        const int rowg = q0 + row;
#pragma unroll
        for (int ps = 0; ps < NP8; ++ps) {
            const int col = ps * 512 + lane * 8;
            const bf16x8 pv8 = *(const bf16x8*)&Ssh[sidx<LKX>(row, col)];
            f32x4 o0, o1;
#pragma unroll
            for (int j = 0; j < 4; ++j) { o0[j] = (float)pv8[j]; o1[j] = (float)pv8[4 + j]; }
            __builtin_nontemporal_store(o0, (f32x4*)&Sout[(size_t)rowg * LKX + col]);
            __builtin_nontemporal_store(o1, (f32x4*)&Sout[(size_t)rowg * LKX + col + 4]);
        }
    }
}

// Merged attention kernel: 8192 blocks; XCD-aware mapping keeps each XCD on
// 8 bh for BOTH branches; c/l blocks interleave in dispatch order.
__global__ __launch_bounds__(256, 3) void fused_attn_all_kernel(
    const bf16_t* __restrict__ Qh, const bf16_t* __restrict__ Kh,
    const bf16_t* __restrict__ Klh,
    const bf16_t* __restrict__ Vt, const bf16_t* __restrict__ Vlt,
    const unsigned* __restrict__ bitc, const unsigned* __restrict__ bitl,
    float* __restrict__ Sc, float* __restrict__ Sl,
    bf16_t* __restrict__ comb_c, bf16_t* __restrict__ comb_l)
{
    __shared__ bf16_t Ssh[16 * LK_];    // 32 KB (l path uses first 16 KB)
    const int bid = blockIdx.x;
    const int xcd = bid & 7;
    const int slot = bid >> 3;
    const int lsel = slot & 1;
    const int sid = xcd * 512 + (slot >> 1);
    if (lsel == 0)
        fused_branch_body<LK_ >(Qh, Kh,  Vt,  bitc, Sc, comb_c, Ssh, sid);
    else
        fused_branch_body<LKL_>(Qh, Klh, Vlt, bitl, Sl, comb_l, Ssh, sid);
}

// ---------------------------------------------------------------------------
// LayerNorm over last dim (1024).
// ---------------------------------------------------------------------------
__global__ __launch_bounds__(256) void ln_kernel(
    const float* __restrict__ Y, const float* __restrict__ g,
    const float* __restrict__ be, float* __restrict__ out)
{
    __shared__ float red1[4], red2[4];
    const int tid = threadIdx.x, wave = tid >> 6, lane = tid & 63;
    const float* p = Y + (size_t)blockIdx.x * DX_;
    const float4 x = *(const float4*)&p[tid * 4];
    float s  = x.x + x.y + x.z + x.w;
    float ss = x.x * x.x + x.y * x.y + x.z * x.z + x.w * x.w;
    s = waveSum(s); ss = waveSum(ss);
    if (lane == 0) { red1[wave] = s; red2[wave] = ss; }
    __syncthreads();
    s  = red1[0] + red1[1] + red1[2] + red1[3];
    ss = red2[0] + red2[1] + red2[2] + red2[3];
    const float mean = s * (1.f / DX_);
    const float var  = ss * (1.f / DX_) - mean * mean;
    const float rstd = rsqrtf(var + EPS_);
    const float4 gg = *(const float4*)&g[tid * 4];
    const float4 bb = *(const float4*)&be[tid * 4];
    float4 o;
    o.x = (x.x - mean) * rstd * gg.x + bb.x;
    o.y = (x.y - mean) * rstd * gg.y + bb.y;
    o.z = (x.z - mean) * rstd * gg.z + bb.z;
    o.w = (x.w - mean) * rstd * gg.w + bb.w;
    *(float4*)&out[(size_t)blockIdx.x * DX_ + tid * 4] = o;
}

// ---------------------------------------------------------------------------
extern "C" void kernel_launch(void* const* d_in, const int* in_sizes, int n_in,
                              void* d_out, int out_size, void* d_ws, size_t ws_size,
                              hipStream_t stream)
{
    const float* q    = (const float*)d_in[0];
    const float* k    = (const float*)d_in[1];
    const float* v    = (const float*)d_in[2];
    const float* kl   = (const float*)d_in[3];
    const float* vl   = (const float*)d_in[4];
    const void*  mask  = d_in[5];
    const void*  maskl = d_in[6];
    const float* wq_w  = (const float*)d_in[7];
    const float* wq_b  = (const float*)d_in[8];
    const float* wk_w  = (const float*)d_in[9];
    const float* wk_b  = (const float*)d_in[10];
    const float* wv_w  = (const float*)d_in[11];
    const float* wv_b  = (const float*)d_in[12];
    const float* wkl_w = (const float*)d_in[13];
    const float* wkl_b = (const float*)d_in[14];
    const float* wvl_w = (const float*)d_in[15];
    const float* wvl_b = (const float*)d_in[16];
    const float* wo_w  = (const float*)d_in[17];
    const float* wo_b  = (const float*)d_in[18];
    const float* ln_g  = (const float*)d_in[19];
    const float* ln_b  = (const float*)d_in[20];

    char* ws = (char*)d_ws;
    const size_t MiB = 1u << 20;
    bf16_t* qb   = (bf16_t*)(ws);                 //  0..8  (dead after proj)
    bf16_t* kb   = (bf16_t*)(ws +   8 * MiB);     //  8..16
    bf16_t* vb   = (bf16_t*)(ws +  16 * MiB);     // 16..24
    bf16_t* klb  = (bf16_t*)(ws +  24 * MiB);     // 24..28
    bf16_t* vlb  = (bf16_t*)(ws +  28 * MiB);     // 28..32
    bf16_t* qh   = (bf16_t*)(ws +  32 * MiB);     // 32..40
    bf16_t* kh   = (bf16_t*)(ws +  40 * MiB);     // 40..48
    bf16_t* klh  = (bf16_t*)(ws +  48 * MiB);     // 48..52
    bf16_t* vh   = (bf16_t*)(ws +  52 * MiB);     // 52..60
    bf16_t* vlh  = (bf16_t*)(ws +  60 * MiB);     // 60..64
    bf16_t* vt   = (bf16_t*)(ws +  64 * MiB);     // 64..72
    bf16_t* vlt  = (bf16_t*)(ws +  72 * MiB);     // 72..76
    bf16_t* wqT  = (bf16_t*)(ws +  76 * MiB);
    bf16_t* wkT  = (bf16_t*)(ws +  78 * MiB);
    bf16_t* wvT  = (bf16_t*)(ws +  80 * MiB);
    bf16_t* wklT = (bf16_t*)(ws +  82 * MiB);
    bf16_t* wvlT = (bf16_t*)(ws +  84 * MiB);
    bf16_t* woT  = (bf16_t*)(ws +  86 * MiB);
    unsigned long long* bitc = (unsigned long long*)(ws + 89 * MiB);
    unsigned long long* bitl = (unsigned long long*)(ws + 89 * MiB + 512 * 1024);
    bf16_t* comb_c = (bf16_t*)(ws +  90 * MiB);   // 90..98
    bf16_t* comb_l = (bf16_t*)(ws +  98 * MiB);   // 98..106
    float*  ypre = (float*) (ws);                 // 0..16 (qb/kb dead)

    float* y_out = (float*)d_out;
    float* Sc = y_out + (size_t)B_ * LQ_ * DX_;
    float* Sl = Sc + (size_t)B_ * H_ * LQ_ * LK_;

    // Mask bit-pack (dtype detection inlined)
    bitpack_mask_kernel<<<dim3((B_*LQ_*(LK_+LKL_)) / 256), 256, 0, stream>>>(
        mask, maskl, bitc, bitl);

    // Activations -> bf16 (one launch)
    {
        CvtArgs a;
        a.src[0] = q;  a.dst[0] = qb;  a.n8[0] = 524288;
        a.src[1] = k;  a.dst[1] = kb;  a.n8[1] = 524288;
        a.src[2] = v;  a.dst[2] = vb;  a.n8[2] = 524288;
        a.src[3] = kl; a.dst[3] = klb; a.n8[3] = 262144;
        a.src[4] = vl; a.dst[4] = vlb; a.n8[4] = 262144;
        cvt_all_kernel<<<dim3(2048, 5), 256, 0, stream>>>(a);
    }

    // Weights -> bf16 transposed (one launch)
    {
        WtArgs a;
        a.W[0] = wq_w;  a.Wt[0] = wqT;
        a.W[1] = wk_w;  a.Wt[1] = wkT;
        a.W[2] = wv_w;  a.Wt[2] = wvT;
        a.W[3] = wkl_w; a.Wt[3] = wklT;
        a.W[4] = wvl_w; a.Wt[4] = wvlT;
        a.W[5] = wo_w;  a.Wt[5] = woT;
        wtrans_all_kernel<<<dim3(16, 16, 6), 256, 0, stream>>>(a);
    }

    // 5 projection GEMMs (one launch)
    {
        ProjArgs a;
        a.A[0] = qb;  a.Bt[0] = wqT;  a.bias[0] = wq_b;  a.out[0] = qh;  a.mt[0] = 32; a.lshift[0] = 10;
        a.A[1] = kb;  a.Bt[1] = wkT;  a.bias[1] = wk_b;  a.out[1] = kh;  a.mt[1] = 32; a.lshift[1] = 10;
        a.A[2] = klb; a.Bt[2] = wklT; a.bias[2] = wkl_b; a.out[2] = klh; a.mt[2] = 16; a.lshift[2] = 9;
        a.A[3] = vb;  a.Bt[3] = wvT;  a.bias[3] = wv_b;  a.out[3] = vh;  a.mt[3] = 32; a.lshift[3] = 10;
        a.A[4] = vlb; a.Bt[4] = wvlT; a.bias[4] = wvl_b; a.out[4] = vlh; a.mt[4] = 16; a.lshift[4] = 9;
        proj_gemm_kernel<<<dim3(8, 32, 5), 512, 0, stream>>>(a);
    }

    // V transposes (one launch)
    {
        TvArgs a;
        a.V[0] = vh;  a.Vt[0] = vt;  a.L[0] = LK_;  a.xt[0] = 16;
        a.V[1] = vlh; a.Vt[1] = vlt; a.L[1] = LKL_; a.xt[1] = 8;
        transpose_v_all_kernel<<<dim3(16, 64, 2), 256, 0, stream>>>(a);
    }

    // Merged attention: both branches in one 8192-block launch.
    fused_attn_all_kernel<<<dim3(8192), 256, 0, stream>>>(
        qh, kh, klh, vt, vlt,
        (const unsigned*)bitc, (const unsigned*)bitl,
        Sc, Sl, comb_c, comb_l);

    // Output projection + bias + residual(q); A = comb_c + comb_l
    out_gemm_kernel<<<dim3(8, 32), 512, 0, stream>>>(comb_c, comb_l, woT, wo_b, ypre, q);

    // LayerNorm
    ln_kernel<<<4096, 256, 0, stream>>>(ypre, ln_g, ln_b, y_out);
}

// Round 10
// 378.130 us; speedup vs baseline: 1.2798x; 1.2798x over previous
//
#include <hip/hip_runtime.h>
#include <hip/hip_bf16.h>

#define B_   4
#define LQ_  1024
#define LK_  1024
#define LKL_ 512
#define DX_  1024
#define H_   16
#define DK_  64
#define HDK_ 1024
#define NEG_ -1e9f
#define EPS_ 1e-5f

typedef __bf16 bf16_t;
typedef __bf16 bf16x8 __attribute__((ext_vector_type(8)));
typedef __bf16 bf16x4 __attribute__((ext_vector_type(4)));
typedef float  f32x4  __attribute__((ext_vector_type(4)));

__device__ inline f32x4 mfma16(bf16x8 a, bf16x8 b, f32x4 c) {
    return __builtin_amdgcn_mfma_f32_16x16x32_bf16(a, b, c, 0, 0, 0);
}

__device__ __forceinline__ void gload16(const void* g, void* l) {
    __builtin_amdgcn_global_load_lds(
        (const __attribute__((address_space(1))) void*)g,
        (__attribute__((address_space(3))) void*)l, 16, 0, 0);
}

__device__ inline float waveMax(float v) {
#pragma unroll
    for (int o = 32; o > 0; o >>= 1) v = fmaxf(v, __shfl_xor(v, o, 64));
    return v;
}
__device__ inline float waveSum(float v) {
#pragma unroll
    for (int o = 32; o > 0; o >>= 1) v += __shfl_xor(v, o, 64);
    return v;
}

// XOR-swizzle: spread column-slice reads across banks (16B slots XOR row).
template<int STRIDE>
__device__ inline int sidx(int row, int col) {
    return (row * STRIDE + col) ^ ((row & 15) << 3);
}

// ---------------------------------------------------------------------------
// Bit-pack both masks (1 = masked), with inline dtype detection.
// ---------------------------------------------------------------------------
__global__ __launch_bounds__(256) void bitpack_mask_kernel(
    const void* __restrict__ mc, const void* __restrict__ ml,
    unsigned long long* __restrict__ bc, unsigned long long* __restrict__ bl)
{
    __shared__ unsigned fl[4];
    {
        const unsigned w = ((const unsigned*)mc)[threadIdx.x];
        const unsigned long long b01 = __ballot(w <= 1u);
        const unsigned long long bfl = __ballot(w == 0u || w == 0x3F800000u);
        if ((threadIdx.x & 63) == 0)
            fl[threadIdx.x >> 6] = ((b01 == ~0ull) ? 1u : 0u) | ((bfl == ~0ull) ? 2u : 0u);
    }
    __syncthreads();
    const unsigned comb = fl[0] & fl[1] & fl[2] & fl[3];
    const unsigned flag = (comb & 1u) ? 0u : ((comb & 2u) ? 2u : 1u);

    const size_t NC = (size_t)B_ * LQ_ * LK_;
    const int lane = threadIdx.x & 63;
    const size_t g = (size_t)blockIdx.x * 256 + threadIdx.x;
    const bool inC = g < NC;
    const size_t idx = inC ? g : g - NC;
    const void* src = inC ? mc : ml;
    bool m;
    if (flag == 0u)      m = ((const int*)src)[idx] != 0;
    else if (flag == 2u) m = ((const float*)src)[idx] != 0.0f;
    else                 m = ((const unsigned char*)src)[idx] != 0;
    const unsigned long long bal = __ballot(m);
    if (lane == 0) {
        unsigned long long* dst = inC ? bc : bl;
        dst[idx >> 6] = bal;
    }
}

// ---------------------------------------------------------------------------
// All 6 weight transposes (KxN f32 -> NxK bf16) in one launch.
// ---------------------------------------------------------------------------
struct WtArgs {
    const float* W[6];
    bf16_t* Wt[6];
};
__global__ __launch_bounds__(256) void wtrans_all_kernel(WtArgs a)
{
    __shared__ float T[64][65];
    const int z = blockIdx.z;
    const float* W = a.W[z];
    bf16_t* Wt = a.Wt[z];
    const int k0 = blockIdx.y * 64, n0 = blockIdx.x * 64;
    const int t = threadIdx.x;
    const int lr = t >> 2, c0 = (t & 3) * 16;
#pragma unroll
    for (int j = 0; j < 4; ++j) {
        const float4 v = *(const float4*)&W[(size_t)(k0 + lr) * DX_ + n0 + c0 + j * 4];
        T[lr][c0 + j * 4 + 0] = v.x; T[lr][c0 + j * 4 + 1] = v.y;
        T[lr][c0 + j * 4 + 2] = v.z; T[lr][c0 + j * 4 + 3] = v.w;
    }
    __syncthreads();
    const int dr = t >> 2;
    bf16x8 o0, o1;
#pragma unroll
    for (int j = 0; j < 8; ++j) {
        o0[j] = (bf16_t)T[c0 + j][dr];
        o1[j] = (bf16_t)T[c0 + 8 + j][dr];
    }
    *(bf16x8*)&Wt[(size_t)(n0 + dr) * DX_ + k0 + c0]     = o0;
    *(bf16x8*)&Wt[(size_t)(n0 + dr) * DX_ + k0 + c0 + 8] = o1;
}

// ---------------------------------------------------------------------------
// Both V transposes (bh, L, 64) -> (bh, 64, L) in one launch.
// ---------------------------------------------------------------------------
struct TvArgs {
    const bf16_t* V[2];
    bf16_t* Vt[2];
    int L[2];
    int xt[2];
};
__global__ __launch_bounds__(256) void transpose_v_all_kernel(TvArgs a)
{
    __shared__ bf16_t T[64][72];
    const int z = blockIdx.z;
    if ((int)blockIdx.x >= a.xt[z]) return;
    const int L = a.L[z];
    const int bh = blockIdx.y, l0 = blockIdx.x * 64;
    const bf16_t* Vb = a.V[z] + (size_t)bh * L * 64;
    bf16_t* Vtb = a.Vt[z] + (size_t)bh * 64 * L;
    const int t = threadIdx.x;
    {
        const int lr = t >> 2, dc = (t & 3) * 16;
        const bf16x8 x = *(const bf16x8*)&Vb[(size_t)(l0 + lr) * 64 + dc];
        const bf16x8 y = *(const bf16x8*)&Vb[(size_t)(l0 + lr) * 64 + dc + 8];
#pragma unroll
        for (int j = 0; j < 8; ++j) { T[lr][dc + j] = x[j]; T[lr][dc + 8 + j] = y[j]; }
    }
    __syncthreads();
    {
        const int dr = t >> 2, lc = (t & 3) * 16;
        bf16x8 o0, o1;
#pragma unroll
        for (int j = 0; j < 8; ++j) { o0[j] = T[lc + j][dr]; o1[j] = T[lc + 8 + j][dr]; }
        *(bf16x8*)&Vtb[(size_t)dr * L + l0 + lc]     = o0;
        *(bf16x8*)&Vtb[(size_t)dr * L + l0 + lc + 8] = o1;
    }
}

// ---------------------------------------------------------------------------
// m97-style GEMM core (128x128 tile, BK=64, 512 threads, XOR-swizzled LDS).
// MODE 0: A is f32 (cvt fused into reg-staged A; B via global_load_lds),
//         output bf16 head layout.
// MODE 2: A is bf16 (global_load_lds), output f32 + residual.
// ---------------------------------------------------------------------------
template<int MODE>
__device__ __forceinline__ void gemm2_body(
    const void* __restrict__ Avoid, const bf16_t* __restrict__ Bt,
    const float* __restrict__ bias,
    void* __restrict__ out, const float* __restrict__ resid, int lshift,
    bf16_t* __restrict__ As, bf16_t* __restrict__ Bs)
{
    char* const AsB = (char*)As;
    char* const BsB = (char*)Bs;
    const int tid = threadIdx.x, wave = tid >> 6, lane = tid & 63;
    const int m0 = blockIdx.y * 128, n0 = blockIdx.x * 128;
    const int wr4 = (wave >> 1) * 32, wc2 = (wave & 1) * 64;

    f32x4 acc[2][4] = {};

    const int srow = wave * 8 + (lane >> 3);
    const int sslot = lane & 7;

    for (int k0 = 0; k0 < 1024; k0 += 64) {
        __syncthreads();
#pragma unroll
        for (int j = 0; j < 2; ++j) {
            const int row = srow + j * 64;
            const int gs = sslot ^ (row & 7);
            if (MODE == 0) {
                const float* Af = (const float*)Avoid;
                const float4* srcp = (const float4*)&Af[(size_t)(m0 + row) * 1024 + k0 + gs * 8];
                const float4 xa = srcp[0], xb = srcp[1];
                bf16x8 t;
                t[0] = (bf16_t)xa.x; t[1] = (bf16_t)xa.y; t[2] = (bf16_t)xa.z; t[3] = (bf16_t)xa.w;
                t[4] = (bf16_t)xb.x; t[5] = (bf16_t)xb.y; t[6] = (bf16_t)xb.z; t[7] = (bf16_t)xb.w;
                *(bf16x8*)(AsB + j * 8192 + wave * 1024 + lane * 16) = t;
            } else {
                const bf16_t* Ab = (const bf16_t*)Avoid;
                gload16(&Ab[(size_t)(m0 + row) * 1024 + k0 + gs * 8],
                        AsB + j * 8192 + wave * 1024);
            }
            gload16(&Bt[(size_t)(n0 + row) * 1024 + k0 + gs * 8],
                    BsB + j * 8192 + wave * 1024);
        }
        __syncthreads();
#pragma unroll
        for (int kk = 0; kk < 2; ++kk) {
            bf16x8 av[2], bv[4];
#pragma unroll
            for (int i = 0; i < 2; ++i) {
                const int r = wr4 + i * 16 + (lane & 15);
                av[i] = *(const bf16x8*)(AsB + r * 128 + (((kk * 4 + (lane >> 4)) ^ (r & 7)) * 16));
            }
#pragma unroll
            for (int n = 0; n < 4; ++n) {
                const int r = wc2 + n * 16 + (lane & 15);
                bv[n] = *(const bf16x8*)(BsB + r * 128 + (((kk * 4 + (lane >> 4)) ^ (r & 7)) * 16));
            }
#pragma unroll
            for (int i = 0; i < 2; ++i)
#pragma unroll
                for (int n = 0; n < 4; ++n)
                    acc[i][n] = mfma16(av[i], bv[n], acc[i][n]);
        }
    }

#pragma unroll
    for (int i = 0; i < 2; ++i) {
#pragma unroll
        for (int n = 0; n < 4; ++n) {
            const int col = n0 + wc2 + n * 16 + (lane & 15);
            const float bs = bias[col];
            const int row0 = m0 + wr4 + i * 16 + (lane >> 4) * 4;
            if (MODE == 0) {
                const int b = row0 >> lshift, l = row0 & ((1 << lshift) - 1);
                const int h = col >> 6, d = col & 63;
#pragma unroll
                for (int r = 0; r < 4; ++r)
                    ((bf16_t*)out)[(((size_t)(b * H_ + h) << lshift) + l + r) * DK_ + d] =
                        (bf16_t)(acc[i][n][r] + bs);
            } else {
#pragma unroll
                for (int r = 0; r < 4; ++r) {
                    const size_t idx = (size_t)(row0 + r) * DX_ + col;
                    ((float*)out)[idx] = acc[i][n][r] + bs + resid[idx];
                }
            }
        }
    }
}

// All 5 projection GEMMs in one launch (z picks operands); A is f32.
struct ProjArgs {
    const float* A[5];
    const bf16_t* Bt[5];
    const float* bias[5];
    bf16_t* out[5];
    int mt[5];
    int lshift[5];
};
__global__ __launch_bounds__(512, 2) void proj_gemm_kernel(ProjArgs a)
{
    __shared__ bf16_t As[128 * 64];
    __shared__ bf16_t Bs[128 * 64];
    const int z = blockIdx.z;
    if ((int)blockIdx.y >= a.mt[z]) return;
    gemm2_body<0>(a.A[z], a.Bt[z], a.bias[z], a.out[z], nullptr, a.lshift[z], As, Bs);
}

// Output projection + bias + residual (A = comb bf16).
__global__ __launch_bounds__(512, 2) void out_gemm_kernel(
    const bf16_t* __restrict__ A, const bf16_t* __restrict__ Bt,
    const float* __restrict__ bias, float* __restrict__ out,
    const float* __restrict__ resid)
{
    __shared__ bf16_t As[128 * 64];
    __shared__ bf16_t Bs[128 * 64];
    gemm2_body<2>(A, Bt, bias, out, resid, 0, As, Bs);
}

// ---------------------------------------------------------------------------
// Attention branch: 16 q-rows/block, 4 waves, LDS = score tile ONLY
// (32 KB c / 16 KB l -> 5 blocks/CU). Mask bits live in registers: each lane
// preloads 1-2 words; score write-back fetches via __shfl broadcast.
// Prob stream-out after the last barrier (no store drain on critical path).
// ---------------------------------------------------------------------------
template<int LKX, bool COMBINE>
__device__ __forceinline__ void fused_branch_body(
    const bf16_t* __restrict__ Qh, const bf16_t* __restrict__ Kh,
    const bf16_t* __restrict__ Vt, const unsigned* __restrict__ bits,
    float* __restrict__ S, bf16_t* __restrict__ comb, bf16_t* __restrict__ Ssh)
{
    const int sid = (blockIdx.x & 7) * 512 + (blockIdx.x >> 3);
    const int bh = sid >> 6, qt = sid & 63;
    const int b = bh >> 4, h = bh & 15;
    const int q0 = qt * 16;
    const int wave = threadIdx.x >> 6, lane = threadIdx.x & 63;
    const int lr = lane & 15, lk8 = (lane >> 4) * 8;
    constexpr int WORDS = LKX / 32;       // bit-words per row
    constexpr int WPS   = LKX / 128;      // words per wave strip (c:8, l:4)

    const bf16_t* Qb  = Qh + (size_t)bh * LQ_ * DK_;
    const bf16_t* Kb  = Kh + (size_t)bh * LKX * DK_;
    const bf16_t* Vtb = Vt + (size_t)bh * DK_ * LKX;
    float* Sout = S + (size_t)bh * LQ_ * LKX;

    // mask bit-words into registers: lane holds word[row = lane&15][wi0(+4)]
    const int pwi = wave * WPS + (lane >> 4);
    const size_t prow_base = (size_t)(b * LQ_ + q0 + (lane & 15)) * WORDS;
    const unsigned w0 = bits[prow_base + pwi];
    unsigned w1 = 0;
    if (WPS == 8) w1 = bits[prow_base + pwi + 4];

    bf16x8 qf[2];
#pragma unroll
    for (int ks = 0; ks < 2; ++ks)
        qf[ks] = *(const bf16x8*)&Qb[(size_t)(q0 + lr) * DK_ + ks * 32 + lk8];

    // ---- scores (masked at write-back; mask word via shfl broadcast) ----
    constexpr int KTS = LKX / 64;
#pragma unroll
    for (int kt = 0; kt < KTS; ++kt) {
        const int kbase = wave * (LKX / 4) + kt * 16;
        const bf16x8 b0 = *(const bf16x8*)&Kb[(size_t)(kbase + lr) * DK_ + lk8];
        const bf16x8 b1 = *(const bf16x8*)&Kb[(size_t)(kbase + lr) * DK_ + 32 + lk8];
        f32x4 acc = {};
        acc = mfma16(qf[0], b0, acc);
        acc = mfma16(qf[1], b1, acc);
        const int d = kt >> 1;                 // word index within strip (compile-time)
        const int sh = (kbase & 16) + (lane & 15);
#pragma unroll
        for (int r = 0; r < 4; ++r) {
            const int row = (lane >> 4) * 4 + r;
            const int srcl = row + ((d & 3) << 4);
            const unsigned word = __shfl((WPS == 8 && d >= 4) ? w1 : w0, srcl, 64);
            const bool msk = (word >> sh) & 1u;
            Ssh[sidx<LKX>(row, kbase + (lane & 15))] = (bf16_t)(msk ? NEG_ : acc[r] * 0.125f);
        }
    }
    __syncthreads();

    // ---- softmax: 4 rows/wave, b128 LDS reads, bf16 probs -> LDS only ----
    constexpr int NP8 = LKX / 512;
#pragma unroll 2
    for (int i = 0; i < 4; ++i) {
        const int row = wave * 4 + i;
        float p[NP8 * 8];
        float m = -INFINITY;
#pragma unroll
        for (int ps = 0; ps < NP8; ++ps) {
            const bf16x8 sv = *(const bf16x8*)&Ssh[sidx<LKX>(row, ps * 512 + lane * 8)];
#pragma unroll
            for (int j = 0; j < 8; ++j) {
                p[ps * 8 + j] = (float)sv[j];
                m = fmaxf(m, p[ps * 8 + j]);
            }
        }
        m = waveMax(m);
        float s = 0.f;
#pragma unroll
        for (int j = 0; j < NP8 * 8; ++j) { p[j] = __expf(p[j] - m); s += p[j]; }
        s = waveSum(s);
        const float inv = 1.f / s;
#pragma unroll
        for (int ps = 0; ps < NP8; ++ps) {
            const int col = ps * 512 + lane * 8;
            bf16x8 pb;
#pragma unroll
            for (int j = 0; j < 8; ++j) pb[j] = (bf16_t)(p[ps * 8 + j] * inv);
            *(bf16x8*)&Ssh[sidx<LKX>(row, col)] = pb;
        }
    }
    __syncthreads();

    // ---- PV ----
    f32x4 acc_o = {};
    const int d0 = wave * 16;
#pragma unroll
    for (int ks = 0; ks < LKX / 32; ++ks) {
        const bf16x8 bb = *(const bf16x8*)&Vtb[(size_t)(d0 + lr) * LKX + ks * 32 + lk8];
        const bf16x8 a  = *(const bf16x8*)&Ssh[sidx<LKX>(lr, ks * 32 + lk8)];
        acc_o = mfma16(a, bb, acc_o);
    }

    // ---- epilogue: comb ----
#pragma unroll
    for (int r = 0; r < 4; ++r) {
        const int row = q0 + (lane >> 4) * 4 + r;
        const size_t idx = ((size_t)b * LQ_ + row) * HDK_ + h * DK_ + d0 + (lane & 15);
        const float half = 0.5f * acc_o[r];
        if (COMBINE) comb[idx] = (bf16_t)((float)comb[idx] + half);
        else         comb[idx] = (bf16_t)half;
    }

    // ---- prob stream-out (after last barrier; fire-and-forget) ----
#pragma unroll
    for (int i = 0; i < 4; ++i) {
        const int row = wave * 4 + i;
        const int rowg = q0 + row;
#pragma unroll
        for (int ps = 0; ps < NP8; ++ps) {
            const int col = ps * 512 + lane * 8;
            const bf16x8 pv8 = *(const bf16x8*)&Ssh[sidx<LKX>(row, col)];
            f32x4 o0, o1;
#pragma unroll
            for (int j = 0; j < 4; ++j) { o0[j] = (float)pv8[j]; o1[j] = (float)pv8[4 + j]; }
            __builtin_nontemporal_store(o0, (f32x4*)&Sout[(size_t)rowg * LKX + col]);
            __builtin_nontemporal_store(o1, (f32x4*)&Sout[(size_t)rowg * LKX + col + 4]);
        }
    }
}

__global__ __launch_bounds__(256, 5) void fused_c_kernel(
    const bf16_t* __restrict__ Qh, const bf16_t* __restrict__ Kh,
    const bf16_t* __restrict__ Vt, const unsigned* __restrict__ bits,
    float* __restrict__ S, bf16_t* __restrict__ comb)
{
    __shared__ bf16_t Ssh[16 * LK_];    // exactly 32 KB -> 5 blocks/CU
    fused_branch_body<LK_, false>(Qh, Kh, Vt, bits, S, comb, Ssh);
}

__global__ __launch_bounds__(256, 5) void fused_l_kernel(
    const bf16_t* __restrict__ Qh, const bf16_t* __restrict__ Kh,
    const bf16_t* __restrict__ Vt, const unsigned* __restrict__ bits,
    float* __restrict__ S, bf16_t* __restrict__ comb)
{
    __shared__ bf16_t Ssh[16 * LKL_];   // exactly 16 KB
    fused_branch_body<LKL_, true>(Qh, Kh, Vt, bits, S, comb, Ssh);
}

// ---------------------------------------------------------------------------
// LayerNorm over last dim (1024).
// ---------------------------------------------------------------------------
__global__ __launch_bounds__(256) void ln_kernel(
    const float* __restrict__ Y, const float* __restrict__ g,
    const float* __restrict__ be, float* __restrict__ out)
{
    __shared__ float red1[4], red2[4];
    const int tid = threadIdx.x, wave = tid >> 6, lane = tid & 63;
    const float* p = Y + (size_t)blockIdx.x * DX_;
    const float4 x = *(const float4*)&p[tid * 4];
    float s  = x.x + x.y + x.z + x.w;
    float ss = x.x * x.x + x.y * x.y + x.z * x.z + x.w * x.w;
    s = waveSum(s); ss = waveSum(ss);
    if (lane == 0) { red1[wave] = s; red2[wave] = ss; }
    __syncthreads();
    s  = red1[0] + red1[1] + red1[2] + red1[3];
    ss = red2[0] + red2[1] + red2[2] + red2[3];
    const float mean = s * (1.f / DX_);
    const float var  = ss * (1.f / DX_) - mean * mean;
    const float rstd = rsqrtf(var + EPS_);
    const float4 gg = *(const float4*)&g[tid * 4];
    const float4 bb = *(const float4*)&be[tid * 4];
    float4 o;
    o.x = (x.x - mean) * rstd * gg.x + bb.x;
    o.y = (x.y - mean) * rstd * gg.y + bb.y;
    o.z = (x.z - mean) * rstd * gg.z + bb.z;
    o.w = (x.w - mean) * rstd * gg.w + bb.w;
    *(float4*)&out[(size_t)blockIdx.x * DX_ + tid * 4] = o;
}

// ---------------------------------------------------------------------------
extern "C" void kernel_launch(void* const* d_in, const int* in_sizes, int n_in,
                              void* d_out, int out_size, void* d_ws, size_t ws_size,
                              hipStream_t stream)
{
    const float* q    = (const float*)d_in[0];
    const float* k    = (const float*)d_in[1];
    const float* v    = (const float*)d_in[2];
    const float* kl   = (const float*)d_in[3];
    const float* vl   = (const float*)d_in[4];
    const void*  mask  = d_in[5];
    const void*  maskl = d_in[6];
    const float* wq_w  = (const float*)d_in[7];
    const float* wq_b  = (const float*)d_in[8];
    const float* wk_w  = (const float*)d_in[9];
    const float* wk_b  = (const float*)d_in[10];
    const float* wv_w  = (const float*)d_in[11];
    const float* wv_b  = (const float*)d_in[12];
    const float* wkl_w = (const float*)d_in[13];
    const float* wkl_b = (const float*)d_in[14];
    const float* wvl_w = (const float*)d_in[15];
    const float* wvl_b = (const float*)d_in[16];
    const float* wo_w  = (const float*)d_in[17];
    const float* wo_b  = (const float*)d_in[18];
    const float* ln_g  = (const float*)d_in[19];
    const float* ln_b  = (const float*)d_in[20];

    char* ws = (char*)d_ws;
    const size_t MiB = 1u << 20;
    float*  ypre = (float*) (ws);                 //  0..16
    bf16_t* qh   = (bf16_t*)(ws +  32 * MiB);     // 32..40
    bf16_t* kh   = (bf16_t*)(ws +  40 * MiB);     // 40..48
    bf16_t* klh  = (bf16_t*)(ws +  48 * MiB);     // 48..52
    bf16_t* vh   = (bf16_t*)(ws +  52 * MiB);     // 52..60
    bf16_t* vlh  = (bf16_t*)(ws +  60 * MiB);     // 60..64
    bf16_t* vt   = (bf16_t*)(ws +  64 * MiB);     // 64..72
    bf16_t* vlt  = (bf16_t*)(ws +  72 * MiB);     // 72..76
    bf16_t* wqT  = (bf16_t*)(ws +  76 * MiB);
    bf16_t* wkT  = (bf16_t*)(ws +  78 * MiB);
    bf16_t* wvT  = (bf16_t*)(ws +  80 * MiB);
    bf16_t* wklT = (bf16_t*)(ws +  82 * MiB);
    bf16_t* wvlT = (bf16_t*)(ws +  84 * MiB);
    bf16_t* woT  = (bf16_t*)(ws +  86 * MiB);
    unsigned long long* bitc = (unsigned long long*)(ws + 89 * MiB);
    unsigned long long* bitl = (unsigned long long*)(ws + 89 * MiB + 512 * 1024);
    bf16_t* comb = (bf16_t*)(ws + 90 * MiB);      // 90..98

    float* y_out = (float*)d_out;
    float* Sc = y_out + (size_t)B_ * LQ_ * DX_;
    float* Sl = Sc + (size_t)B_ * H_ * LQ_ * LK_;

    // Mask bit-pack (dtype detection inlined)
    bitpack_mask_kernel<<<dim3((B_*LQ_*(LK_+LKL_)) / 256), 256, 0, stream>>>(
        mask, maskl, bitc, bitl);

    // Weights -> bf16 transposed (one launch)
    {
        WtArgs a;
        a.W[0] = wq_w;  a.Wt[0] = wqT;
        a.W[1] = wk_w;  a.Wt[1] = wkT;
        a.W[2] = wv_w;  a.Wt[2] = wvT;
        a.W[3] = wkl_w; a.Wt[3] = wklT;
        a.W[4] = wvl_w; a.Wt[4] = wvlT;
        a.W[5] = wo_w;  a.Wt[5] = woT;
        wtrans_all_kernel<<<dim3(16, 16, 6), 256, 0, stream>>>(a);
    }

    // 5 projection GEMMs, f32 A with fused cvt (one launch)
    {
        ProjArgs a;
        a.A[0] = q;  a.Bt[0] = wqT;  a.bias[0] = wq_b;  a.out[0] = qh;  a.mt[0] = 32; a.lshift[0] = 10;
        a.A[1] = k;  a.Bt[1] = wkT;  a.bias[1] = wk_b;  a.out[1] = kh;  a.mt[1] = 32; a.lshift[1] = 10;
        a.A[2] = kl; a.Bt[2] = wklT; a.bias[2] = wkl_b; a.out[2] = klh; a.mt[2] = 16; a.lshift[2] = 9;
        a.A[3] = v;  a.Bt[3] = wvT;  a.bias[3] = wv_b;  a.out[3] = vh;  a.mt[3] = 32; a.lshift[3] = 10;
        a.A[4] = vl; a.Bt[4] = wvlT; a.bias[4] = wvl_b; a.out[4] = vlh; a.mt[4] = 16; a.lshift[4] = 9;
        proj_gemm_kernel<<<dim3(8, 32, 5), 512, 0, stream>>>(a);
    }

    // V transposes (one launch)
    {
        TvArgs a;
        a.V[0] = vh;  a.Vt[0] = vt;  a.L[0] = LK_;  a.xt[0] = 16;
        a.V[1] = vlh; a.Vt[1] = vlt; a.L[1] = LKL_; a.xt[1] = 8;
        transpose_v_all_kernel<<<dim3(16, 64, 2), 256, 0, stream>>>(a);
    }

    // Attention branch c (writes Sc + comb = 0.5*Oc), then branch l
    // (writes Sl, comb += 0.5*Ol). Kernels serialize on the stream.
    fused_c_kernel<<<dim3(4096), 256, 0, stream>>>(qh, kh,  vt,  (const unsigned*)bitc, Sc, comb);
    fused_l_kernel<<<dim3(4096), 256, 0, stream>>>(qh, klh, vlt, (const unsigned*)bitl, Sl, comb);

    // Output projection + bias + residual(q)
    out_gemm_kernel<<<dim3(8, 32), 512, 0, stream>>>(comb, woT, wo_b, ypre, q);

    // LayerNorm
    ln_kernel<<<4096, 256, 0, stream>>>(ypre, ln_g, ln_b, y_out);
}